// Round 6
// baseline (369.846 us; speedup 1.0000x reference)
//
#include <hip/hip_runtime.h>

#define B_ 8
#define S_ 2048
#define M_ 256
#define D_ 512
#define P_ 512
#define H_ 8

#define SCALE 0.044194173824159216f  // 1/sqrt(512)

typedef __attribute__((ext_vector_type(8))) short bf16x8;
typedef __attribute__((ext_vector_type(4))) float f32x4;

static __device__ __forceinline__ float bf2f(short u) {
  union { float f; unsigned int i; } x;
  x.i = ((unsigned int)(unsigned short)u) << 16;
  return x.f;
}
static __device__ __forceinline__ short f2bf(float f) {
  union { float f; unsigned int i; } x;
  x.f = f;
  unsigned int r = (x.i + 0x7FFFu + ((x.i >> 16) & 1u)) >> 16;
  return (short)r;
}

// async global->LDS, 16B per lane; lds base must be wave-uniform
static __device__ __forceinline__ void gll16(const short* g, short* l) {
  __builtin_amdgcn_global_load_lds(
      (const __attribute__((address_space(1))) void*)g,
      (__attribute__((address_space(3))) void*)l, 16, 0, 0);
}

#define LGKM_WAIT() asm volatile("s_waitcnt lgkmcnt(0)" ::: "memory")

// ---------------------------------------------------------------------------
// fused fp32 -> bf16 cast (RNE) for input_seq and memory_cells
// ---------------------------------------------------------------------------
__global__ __launch_bounds__(256) void cast_both(
    const float* __restrict__ inA, short* __restrict__ outA, int n4A,
    const float* __restrict__ inM, short* __restrict__ outM)
{
  int idx = blockIdx.x * 256 + threadIdx.x;
  const float* in = inA;
  short* out = outA;
  if (idx >= n4A) { idx -= n4A; in = inM; out = outM; }
  float4 v = ((const float4*)in)[idx];
  short o0 = f2bf(v.x), o1 = f2bf(v.y), o2 = f2bf(v.z), o3 = f2bf(v.w);
  uint2 pk;
  pk.x = (unsigned int)(unsigned short)o0 | ((unsigned int)(unsigned short)o1 << 16);
  pk.y = (unsigned int)(unsigned short)o2 | ((unsigned int)(unsigned short)o3 << 16);
  ((uint2*)out)[idx] = pk;
}

// ---------------------------------------------------------------------------
// weight transpose+cast: in fp32 [kdim][ndim] (+z*kdim*ndim) -> out bf16 [n][k]
// ---------------------------------------------------------------------------
__global__ __launch_bounds__(256) void wtrans_g(
    const float* __restrict__ in, short* __restrict__ out, int kdim, int ndim)
{
  __shared__ float tile[32][33];
  const int t = threadIdx.x, tx = t & 31, ty = t >> 5;
  const size_t zofs = (size_t)blockIdx.z * kdim * ndim;
  const int n0 = blockIdx.x * 32, k0 = blockIdx.y * 32;
  const float* inp = in + zofs;
  short* outp = out + zofs;
#pragma unroll
  for (int i = 0; i < 4; ++i)
    tile[ty + 8 * i][tx] = inp[(size_t)(k0 + ty + 8 * i) * ndim + n0 + tx];
  __syncthreads();
#pragma unroll
  for (int i = 0; i < 4; ++i)
    outp[(size_t)(n0 + ty + 8 * i) * kdim + k0 + tx] = f2bf(tile[tx][ty + 8 * i]);
}

// ---------------------------------------------------------------------------
// zero Ls (16384 floats)
// ---------------------------------------------------------------------------
__global__ __launch_bounds__(256) void zero_f(float* __restrict__ p) {
  ((float4*)p)[blockIdx.x * 256 + threadIdx.x] = make_float4(0.f, 0.f, 0.f, 0.f);
}

// ---------------------------------------------------------------------------
// m97-style 128x128 MFMA GEMM template. A[m][lda] bf16, B[n][ldb] bf16.
// BK=32, global_load_lds width-16 staging, XOR-swizzled LDS for the K-loop.
// bf16 epilogues go through a per-wave LDS staging tile (32 rows x 72 stride)
// so global stores are 64 B/lane fully-coalesced lines (no partial-line RFO).
// MODE 1: C bf16 = acc + bias[z*512+col], rows scattered (b*8+z)*256+(row&255)
// MODE 2: C bf16 = exp(acc*SCALE), fused row-sum atomicAdd into Ls  (QK -> E)
// MODE 3: C bf16 = (acc + eself*mv)*inv, concat-layout scatter (PV+normalize)
// MODE 5: fp32 partial at Cv[z*cZ + row*N + col]   (Wo split-K slice z)
// ---------------------------------------------------------------------------
template<int MODE>
__global__ __launch_bounds__(256) void gemm128(
    const short* __restrict__ Abase, const short* __restrict__ Bbase,
    const float* __restrict__ bias, void* __restrict__ Cv,
    const int K, const int N, const int lda, const int ldb,
    const size_t aZ, const int bzsh, const size_t bZ, const size_t cZ,
    const int biasZ, float* __restrict__ Ls,
    const float* __restrict__ eselfp, const short* __restrict__ mvbp)
{
  __shared__ short As[4096];  // 128 rows x 32 k
  __shared__ short Bs[4096];
  __shared__ __align__(16) short Ep[4][2304];  // per-wave 32 x 72 epilogue tile
  const int t = threadIdx.x;
  const int w = t >> 6, lane = t & 63, qd = lane >> 4, ln = lane & 15;
  const int z = blockIdx.z;
  const int n0 = blockIdx.x * 128, m0 = blockIdx.y * 128;
  const int wm = (w & 1) * 64, wn = (w >> 1) * 64;

  const short* A  = Abase + (size_t)z * aZ;
  const short* Bp = Bbase + (size_t)(z >> bzsh) * bZ;

  const int r0 = t >> 2, g0 = t & 3;
  const int r1 = r0 + 64;
  const int gs0 = g0 ^ ((r0 >> 1) & 3);
  const int gs1 = g0 ^ ((r1 >> 1) & 3);
  short* ldsA0 = &As[(size_t)(w * 512)];
  short* ldsA1 = &As[(size_t)(2048 + w * 512)];
  short* ldsB0 = &Bs[(size_t)(w * 512)];
  short* ldsB1 = &Bs[(size_t)(2048 + w * 512)];

  const short* ga0 = A + (size_t)(m0 + r0) * lda + gs0 * 8;
  const short* ga1 = A + (size_t)(m0 + r1) * lda + gs1 * 8;
  const short* gb0 = Bp + (size_t)(n0 + r0) * ldb + gs0 * 8;
  const short* gb1 = Bp + (size_t)(n0 + r1) * ldb + gs1 * 8;

  int aoff[4], boff[4];
#pragma unroll
  for (int mt = 0; mt < 4; ++mt) {
    int r = wm + mt * 16 + ln;
    aoff[mt] = r * 32 + (qd ^ ((r >> 1) & 3)) * 8;
  }
#pragma unroll
  for (int nt = 0; nt < 4; ++nt) {
    int r = wn + nt * 16 + ln;
    boff[nt] = r * 32 + (qd ^ ((r >> 1) & 3)) * 8;
  }

  f32x4 acc[4][4];
#pragma unroll
  for (int mt = 0; mt < 4; ++mt)
#pragma unroll
    for (int nt = 0; nt < 4; ++nt) acc[mt][nt] = (f32x4){0.f, 0.f, 0.f, 0.f};

  for (int kc = 0; kc < K; kc += 32) {
    __syncthreads();
    gll16(ga0 + kc, ldsA0);
    gll16(ga1 + kc, ldsA1);
    gll16(gb0 + kc, ldsB0);
    gll16(gb1 + kc, ldsB1);
    __syncthreads();

    bf16x8 af[4], bfr[4];
#pragma unroll
    for (int mt = 0; mt < 4; ++mt) af[mt] = *(const bf16x8*)&As[aoff[mt]];
#pragma unroll
    for (int nt = 0; nt < 4; ++nt) bfr[nt] = *(const bf16x8*)&Bs[boff[nt]];
#pragma unroll
    for (int mt = 0; mt < 4; ++mt)
#pragma unroll
      for (int nt = 0; nt < 4; ++nt)
        acc[mt][nt] = __builtin_amdgcn_mfma_f32_16x16x32_bf16(af[mt], bfr[nt], acc[mt][nt], 0, 0, 0);
  }

  if constexpr (MODE == 5) {
#pragma unroll
    for (int nt = 0; nt < 4; ++nt) {
      const int col = n0 + wn + nt * 16 + ln;
#pragma unroll
      for (int mt = 0; mt < 4; ++mt) {
#pragma unroll
        for (int r = 0; r < 4; ++r) {
          const int row = m0 + wm + mt * 16 + qd * 4 + r;
          ((float*)Cv)[(size_t)z * cZ + (size_t)row * N + col] = acc[mt][nt][r];
        }
      }
    }
    return;
  }

  if constexpr (MODE == 2) {
    // exp in-place, then fused row-sum -> Ls
#pragma unroll
    for (int mt = 0; mt < 4; ++mt)
#pragma unroll
      for (int nt = 0; nt < 4; ++nt)
#pragma unroll
        for (int r = 0; r < 4; ++r)
          acc[mt][nt][r] = __expf(acc[mt][nt][r] * SCALE);
#pragma unroll
    for (int mt = 0; mt < 4; ++mt)
#pragma unroll
      for (int r = 0; r < 4; ++r) {
        float rsum = acc[mt][0][r] + acc[mt][1][r] + acc[mt][2][r] + acc[mt][3][r];
        rsum += __shfl_xor(rsum, 1);
        rsum += __shfl_xor(rsum, 2);
        rsum += __shfl_xor(rsum, 4);
        rsum += __shfl_xor(rsum, 8);
        if (ln == 0) {
          const int row = m0 + wm + mt * 16 + qd * 4 + r;
          atomicAdd(&Ls[(size_t)z * M_ + row], rsum);
        }
      }
  }

  // ---- LDS-staged coalesced epilogue (bf16 modes) ----
  short* ep = Ep[w];
  const int lr = lane >> 1, lc = (lane & 1) * 32;
#pragma unroll
  for (int pass = 0; pass < 2; ++pass) {
#pragma unroll
    for (int mh = 0; mh < 2; ++mh) {
      const int mt = pass * 2 + mh;
#pragma unroll
      for (int nt = 0; nt < 4; ++nt) {
        float bc = 0.f;
        if constexpr (MODE == 1) bc = bias[biasZ * z + n0 + wn + nt * 16 + ln];
#pragma unroll
        for (int r = 0; r < 4; ++r)
          ep[(mh * 16 + qd * 4 + r) * 72 + nt * 16 + ln] = f2bf(acc[mt][nt][r] + bc);
      }
    }
    LGKM_WAIT();
    const int grl = m0 + wm + pass * 32 + lr;   // local row within A-tile rows
    const int cb = n0 + wn + lc;
    if constexpr (MODE == 1) {
      const int bidx = grl >> 8, ml = grl & 255;
      short* outp = (short*)Cv + ((size_t)(bidx * H_ + z) * M_ + ml) * N + cb;
#pragma unroll
      for (int u = 0; u < 4; ++u)
        *(bf16x8*)(outp + u * 8) = *(const bf16x8*)&ep[lr * 72 + lc + u * 8];
    } else if constexpr (MODE == 2) {
      short* outp = (short*)Cv + (size_t)z * cZ + (size_t)grl * N + cb;
#pragma unroll
      for (int u = 0; u < 4; ++u)
        *(bf16x8*)(outp + u * 8) = *(const bf16x8*)&ep[lr * 72 + lc + u * 8];
    } else {  // MODE 3: PV + normalize + concat scatter
      const int zb = z >> 3, h = z & 7;
      const float es = eselfp[(size_t)z * M_ + grl];
      const float inv = 1.f / (es + Ls[(size_t)z * M_ + grl]);
      const short* mvr = mvbp + ((size_t)(zb * M_ + grl)) * P_ + cb;
      short* outp = (short*)Cv + ((size_t)(zb * M_ + grl)) * (H_ * P_) + (size_t)h * P_ + cb;
#pragma unroll
      for (int u = 0; u < 4; ++u) {
        bf16x8 evv = *(const bf16x8*)&ep[lr * 72 + lc + u * 8];
        bf16x8 mvv = *(const bf16x8*)(mvr + u * 8);
        bf16x8 o8;
#pragma unroll
        for (int j = 0; j < 8; ++j)
          o8[j] = f2bf((bf2f(evv[j]) + es * bf2f(mvv[j])) * inv);
        *(bf16x8*)(outp + u * 8) = o8;
      }
    }
    LGKM_WAIT();
  }
}

// ---------------------------------------------------------------------------
// merged K/V projection: Ck = A@WkT + bk (row-major), V = A@WvT + bv.
// TRANSV=false: V row-major to Cvv.  TRANSV=true: V written transposed
// directly into ivT (B,P,S) — removes the separate ivtrans pass.
// Block 128m x 64n, wave = 64m x 32n for both outputs. LDS-staged epilogues.
// ---------------------------------------------------------------------------
template<bool TRANSV>
__global__ __launch_bounds__(256) void proj_kv(
    const short* __restrict__ A,
    const short* __restrict__ WkT, const short* __restrict__ WvT,
    const float* __restrict__ bk, const float* __restrict__ bv,
    short* __restrict__ Ck, short* __restrict__ Cvv)
{
  __shared__ short As[4096];   // 128 x 32
  __shared__ short Bks[2048];  // 64 x 32
  __shared__ short Bvs[2048];
  __shared__ __align__(16) short Ep[4][1280];  // per-wave 32 x 40
  const int t = threadIdx.x;
  const int w = t >> 6, lane = t & 63, qd = lane >> 4, ln = lane & 15;
  const int n0 = blockIdx.x * 64, m0 = blockIdx.y * 128;
  const int wm = (w & 1) * 64, wn2 = (w >> 1) * 32;

  const int r0 = t >> 2, g0 = t & 3;
  const int r1 = r0 + 64;
  const int gs0 = g0 ^ ((r0 >> 1) & 3);
  const int gs1 = g0 ^ ((r1 >> 1) & 3);

  short* ldsA0 = &As[(size_t)(w * 512)];
  short* ldsA1 = &As[(size_t)(2048 + w * 512)];
  short* ldsBk = &Bks[(size_t)(w * 512)];
  short* ldsBv = &Bvs[(size_t)(w * 512)];

  const short* ga0 = A + (size_t)(m0 + r0) * 512 + gs0 * 8;
  const short* ga1 = A + (size_t)(m0 + r1) * 512 + gs1 * 8;
  const short* gbk = WkT + (size_t)(n0 + r0) * 512 + gs0 * 8;
  const short* gbv = WvT + (size_t)(n0 + r0) * 512 + gs0 * 8;

  int aoff[4], boff[2];
#pragma unroll
  for (int mt = 0; mt < 4; ++mt) {
    int r = wm + mt * 16 + ln;
    aoff[mt] = r * 32 + (qd ^ ((r >> 1) & 3)) * 8;
  }
#pragma unroll
  for (int nt = 0; nt < 2; ++nt) {
    int r = wn2 + nt * 16 + ln;
    boff[nt] = r * 32 + (qd ^ ((r >> 1) & 3)) * 8;
  }

  f32x4 accK[4][2], accV[4][2];
#pragma unroll
  for (int mt = 0; mt < 4; ++mt)
#pragma unroll
    for (int nt = 0; nt < 2; ++nt) {
      accK[mt][nt] = (f32x4){0.f, 0.f, 0.f, 0.f};
      accV[mt][nt] = (f32x4){0.f, 0.f, 0.f, 0.f};
    }

  for (int kc = 0; kc < 512; kc += 32) {
    __syncthreads();
    gll16(ga0 + kc, ldsA0);
    gll16(ga1 + kc, ldsA1);
    gll16(gbk + kc, ldsBk);
    gll16(gbv + kc, ldsBv);
    __syncthreads();

    bf16x8 af[4], bkf[2], bvf[2];
#pragma unroll
    for (int mt = 0; mt < 4; ++mt) af[mt] = *(const bf16x8*)&As[aoff[mt]];
#pragma unroll
    for (int nt = 0; nt < 2; ++nt) {
      bkf[nt] = *(const bf16x8*)&Bks[boff[nt]];
      bvf[nt] = *(const bf16x8*)&Bvs[boff[nt]];
    }
#pragma unroll
    for (int mt = 0; mt < 4; ++mt)
#pragma unroll
      for (int nt = 0; nt < 2; ++nt) {
        accK[mt][nt] = __builtin_amdgcn_mfma_f32_16x16x32_bf16(af[mt], bkf[nt], accK[mt][nt], 0, 0, 0);
        accV[mt][nt] = __builtin_amdgcn_mfma_f32_16x16x32_bf16(af[mt], bvf[nt], accV[mt][nt], 0, 0, 0);
      }
  }

  short* ep = Ep[w];
  const int lr = lane >> 1, lc16 = (lane & 1) * 16;
#pragma unroll
  for (int pass = 0; pass < 2; ++pass) {
    const int grl = m0 + wm + pass * 32 + lr;
    // ---- K output (row-major)
#pragma unroll
    for (int mh = 0; mh < 2; ++mh) {
      const int mt = pass * 2 + mh;
#pragma unroll
      for (int nt = 0; nt < 2; ++nt) {
        const float bc = bk[n0 + wn2 + nt * 16 + ln];
#pragma unroll
        for (int r = 0; r < 4; ++r)
          ep[(mh * 16 + qd * 4 + r) * 40 + nt * 16 + ln] = f2bf(accK[mt][nt][r] + bc);
      }
    }
    LGKM_WAIT();
    {
      short* outp = Ck + (size_t)grl * 512 + n0 + wn2 + lc16;
      *(bf16x8*)outp = *(const bf16x8*)&ep[lr * 40 + lc16];
      *(bf16x8*)(outp + 8) = *(const bf16x8*)&ep[lr * 40 + lc16 + 8];
    }
    LGKM_WAIT();
    // ---- V output
    if constexpr (!TRANSV) {
#pragma unroll
      for (int mh = 0; mh < 2; ++mh) {
        const int mt = pass * 2 + mh;
#pragma unroll
        for (int nt = 0; nt < 2; ++nt) {
          const float bc = bv[n0 + wn2 + nt * 16 + ln];
#pragma unroll
          for (int r = 0; r < 4; ++r)
            ep[(mh * 16 + qd * 4 + r) * 40 + nt * 16 + ln] = f2bf(accV[mt][nt][r] + bc);
        }
      }
      LGKM_WAIT();
      short* outp = Cvv + (size_t)grl * 512 + n0 + wn2 + lc16;
      *(bf16x8*)outp = *(const bf16x8*)&ep[lr * 40 + lc16];
      *(bf16x8*)(outp + 8) = *(const bf16x8*)&ep[lr * 40 + lc16 + 8];
      LGKM_WAIT();
    } else {
      // write LDS tile transposed [p 32][s 32]
#pragma unroll
      for (int mh = 0; mh < 2; ++mh) {
        const int mt = pass * 2 + mh;
#pragma unroll
        for (int nt = 0; nt < 2; ++nt) {
          const float bc = bv[n0 + wn2 + nt * 16 + ln];
#pragma unroll
          for (int r = 0; r < 4; ++r)
            ep[(nt * 16 + ln) * 40 + mh * 16 + qd * 4 + r] = f2bf(accV[mt][nt][r] + bc);
        }
      }
      LGKM_WAIT();
      const int srow0 = m0 + wm + pass * 32;     // global s start of chunk
      const int bidx = srow0 >> 11;              // batch (2048 rows each)
      const int sloc = (srow0 & 2047) + lc16;
      const int pcol = n0 + wn2 + lr;
      short* outp = Cvv + (size_t)bidx * P_ * S_ + (size_t)pcol * S_ + sloc;
      *(bf16x8*)outp = *(const bf16x8*)&ep[lr * 40 + lc16];
      *(bf16x8*)(outp + 8) = *(const bf16x8*)&ep[lr * 40 + lc16 + 8];
      LGKM_WAIT();
    }
  }
}

// ---------------------------------------------------------------------------
// split-K reduce for Wo: out = sum_z partial[z] + bo[col], fp32
// ---------------------------------------------------------------------------
__global__ __launch_bounds__(256) void reduce_wo(
    const float* __restrict__ partial, const float* __restrict__ bo,
    float* __restrict__ out)
{
  const int idx4 = blockIdx.x * 256 + threadIdx.x;   // float4 index, 262144
  float4 s = ((const float4*)bo)[idx4 & 127];
#pragma unroll
  for (int zz = 0; zz < 4; ++zz) {
    float4 p = ((const float4*)partial)[(size_t)zz * 262144 + idx4];
    s.x += p.x; s.y += p.y; s.z += p.z; s.w += p.w;
  }
  ((float4*)out)[idx4] = s;
}

// ---------------------------------------------------------------------------
// self-score: eself[z*256+m] = exp(scale * q[z][m][:] . mk[b][m][:])
// ---------------------------------------------------------------------------
__global__ __launch_bounds__(256) void selfscore(
    const short* __restrict__ qb, const short* __restrict__ mkb,
    float* __restrict__ eself)
{
  const int z = blockIdx.x, t = threadIdx.x;
  const short* qr = qb + ((size_t)z * M_ + t) * P_;
  const short* mr = mkb + ((size_t)(z >> 3) * M_ + t) * P_;
  float s = 0.f;
#pragma unroll 8
  for (int c = 0; c < P_; c += 8) {
    bf16x8 qv = *(const bf16x8*)(qr + c);
    bf16x8 mv = *(const bf16x8*)(mr + c);
#pragma unroll
    for (int j = 0; j < 8; ++j) s += bf2f(qv[j]) * bf2f(mv[j]);
  }
  eself[(size_t)z * M_ + t] = __expf(s * SCALE);
}

// ---------------------------------------------------------------------------
extern "C" void kernel_launch(void* const* d_in, const int* in_sizes, int n_in,
                              void* d_out, int out_size, void* d_ws, size_t ws_size,
                              hipStream_t stream) {
  const float* input_seq = (const float*)d_in[0];
  const float* memcells  = (const float*)d_in[1];
  const float* Wk = (const float*)d_in[2];
  const float* bk = (const float*)d_in[3];
  const float* Wv = (const float*)d_in[4];
  const float* bv = (const float*)d_in[5];
  const float* Wq = (const float*)d_in[6];
  const float* bq = (const float*)d_in[7];
  const float* Wo = (const float*)d_in[8];
  const float* bo = (const float*)d_in[9];
  float* out = (float*)d_out;

  // ---- workspace carve (shorts). region2 time-shared: {Ab,Mb,W*T} dead
  // before Eb written. 'partial' region reused for Wo split-K fp32 partials.
  short* ws = (short*)d_ws;
  size_t o = 0;
  short* valb = ws + o; o += (size_t)B_ * M_ * H_ * P_;      // 8388608
  short* WoT  = ws + o; o += (size_t)(H_ * P_) * P_;          // 2097152
  short* mvb  = ws + o; o += (size_t)B_ * M_ * P_;            // 1048576
  short* mkb  = ws + o; o += (size_t)B_ * M_ * P_;            // 1048576
  short* qb   = ws + o; o += (size_t)B_ * H_ * M_ * P_;       // 8388608
  short* ivT  = ws + o; o += (size_t)B_ * P_ * S_;            // 8388608
  short* ikb  = ws + o; o += (size_t)B_ * S_ * P_;            // 8388608
  float* partial = (float*)(ws + o); o += (size_t)B_ * H_ * M_ * P_;  // 16 MB
  float* eself = (float*)(ws + o); o += 2 * (size_t)B_ * H_ * M_;
  float* Ls    = (float*)(ws + o); o += 2 * (size_t)B_ * H_ * M_;
  short* region2 = ws + o;                                    // Eb region (64 MB)
  short* Ab  = region2;
  short* Mb  = Ab + (size_t)B_ * S_ * D_;
  short* WkT = Mb + (size_t)B_ * M_ * D_;
  short* WvT = WkT + (size_t)D_ * P_;
  short* WqT = WvT + (size_t)D_ * P_;
  short* Eb  = region2;   // overlaps the above (all dead before E is written)

  dim3 blk(256);

  // casts + weight transposes
  const int n4A = B_ * S_ * D_ / 4;
  const int n4M = B_ * M_ * D_ / 4;
  cast_both<<<dim3((n4A + n4M) / 256), blk, 0, stream>>>(input_seq, Ab, n4A, memcells, Mb);
  wtrans_g<<<dim3(16, 16, 1), blk, 0, stream>>>(Wk, WkT, 512, 512);
  wtrans_g<<<dim3(16, 16, 1), blk, 0, stream>>>(Wv, WvT, 512, 512);
  wtrans_g<<<dim3(16, 16, 8), blk, 0, stream>>>(Wq, WqT, 512, 512);
  wtrans_g<<<dim3(16, 128, 1), blk, 0, stream>>>(Wo, WoT, 4096, 512);

  // merged K/V projections; big one emits ivT directly (transposed V)
  proj_kv<true><<<dim3(8, 128), blk, 0, stream>>>(Ab, WkT, WvT, bk, bv, ikb, ivT);
  proj_kv<false><<<dim3(8, 16), blk, 0, stream>>>(Mb, WkT, WvT, bk, bv, mkb, mvb);

  // q projection: MODE 1, z = h
  gemm128<1><<<dim3(4, 16, 8), blk, 0, stream>>>(
      Mb, WqT, bq, qb, 512, 512, 512, 512,
      0, 0, (size_t)D_ * P_, 0, 512, nullptr, nullptr, nullptr);

  // zero Ls, then E = exp(scale * q @ ik^T) with fused row-sum
  zero_f<<<dim3(16), blk, 0, stream>>>(Ls);
  gemm128<2><<<dim3(16, 2, 64), blk, 0, stream>>>(
      qb, ikb, nullptr, Eb, 512, 2048, 512, 512,
      (size_t)M_ * P_, 3, (size_t)S_ * P_, (size_t)M_ * S_, 0, Ls, nullptr, nullptr);

  // eself
  selfscore<<<dim3(64), blk, 0, stream>>>(qb, mkb, eself);

  // val = normalize(E @ iv + eself*mv) fused, concat layout
  gemm128<3><<<dim3(4, 2, 64), blk, 0, stream>>>(
      Eb, ivT, nullptr, valb, 2048, 512, 2048, 2048,
      (size_t)M_ * S_, 3, (size_t)P_ * S_, 0, 0, Ls, eself, mvb);

  // Wo: split-K=4 partials (grid 256 blocks), then reduce+bias
  gemm128<5><<<dim3(4, 16, 4), blk, 0, stream>>>(
      valb, WoT, nullptr, partial, 1024, 512, 4096, 4096,
      1024, 0, 1024, (size_t)2048 * 512, 0, nullptr, nullptr, nullptr);
  reduce_wo<<<dim3(1024), blk, 0, stream>>>(partial, bo, out);
}

// Round 7
// 325.648 us; speedup vs baseline: 1.1357x; 1.1357x over previous
//
#include <hip/hip_runtime.h>

#define B_ 8
#define S_ 2048
#define M_ 256
#define D_ 512
#define P_ 512
#define H_ 8

#define SCALE 0.044194173824159216f  // 1/sqrt(512)

typedef __attribute__((ext_vector_type(8))) short bf16x8;
typedef __attribute__((ext_vector_type(4))) float f32x4;

static __device__ __forceinline__ float bf2f(short u) {
  union { float f; unsigned int i; } x;
  x.i = ((unsigned int)(unsigned short)u) << 16;
  return x.f;
}
static __device__ __forceinline__ short f2bf(float f) {
  union { float f; unsigned int i; } x;
  x.f = f;
  unsigned int r = (x.i + 0x7FFFu + ((x.i >> 16) & 1u)) >> 16;
  return (short)r;
}

// async global->LDS, 16B per lane; lds base must be wave-uniform
static __device__ __forceinline__ void gll16(const short* g, short* l) {
  __builtin_amdgcn_global_load_lds(
      (const __attribute__((address_space(1))) void*)g,
      (__attribute__((address_space(3))) void*)l, 16, 0, 0);
}

#define LGKM_WAIT() asm volatile("s_waitcnt lgkmcnt(0)" ::: "memory")

// ---------------------------------------------------------------------------
// fused fp32 -> bf16 cast (RNE) for input_seq and memory_cells
// ---------------------------------------------------------------------------
__global__ __launch_bounds__(256) void cast_both(
    const float* __restrict__ inA, short* __restrict__ outA, int n4A,
    const float* __restrict__ inM, short* __restrict__ outM)
{
  int idx = blockIdx.x * 256 + threadIdx.x;
  const float* in = inA;
  short* out = outA;
  if (idx >= n4A) { idx -= n4A; in = inM; out = outM; }
  float4 v = ((const float4*)in)[idx];
  short o0 = f2bf(v.x), o1 = f2bf(v.y), o2 = f2bf(v.z), o3 = f2bf(v.w);
  uint2 pk;
  pk.x = (unsigned int)(unsigned short)o0 | ((unsigned int)(unsigned short)o1 << 16);
  pk.y = (unsigned int)(unsigned short)o2 | ((unsigned int)(unsigned short)o3 << 16);
  ((uint2*)out)[idx] = pk;
}

// ---------------------------------------------------------------------------
// weight transpose+cast: in fp32 [kdim][ndim] (+z*kdim*ndim) -> out bf16 [n][k]
// ---------------------------------------------------------------------------
__global__ __launch_bounds__(256) void wtrans_g(
    const float* __restrict__ in, short* __restrict__ out, int kdim, int ndim)
{
  __shared__ float tile[32][33];
  const int t = threadIdx.x, tx = t & 31, ty = t >> 5;
  const size_t zofs = (size_t)blockIdx.z * kdim * ndim;
  const int n0 = blockIdx.x * 32, k0 = blockIdx.y * 32;
  const float* inp = in + zofs;
  short* outp = out + zofs;
#pragma unroll
  for (int i = 0; i < 4; ++i)
    tile[ty + 8 * i][tx] = inp[(size_t)(k0 + ty + 8 * i) * ndim + n0 + tx];
  __syncthreads();
#pragma unroll
  for (int i = 0; i < 4; ++i)
    outp[(size_t)(n0 + ty + 8 * i) * kdim + k0 + tx] = f2bf(tile[tx][ty + 8 * i]);
}

// ---------------------------------------------------------------------------
// zero Ls (16384 floats)
// ---------------------------------------------------------------------------
__global__ __launch_bounds__(256) void zero_f(float* __restrict__ p) {
  ((float4*)p)[blockIdx.x * 256 + threadIdx.x] = make_float4(0.f, 0.f, 0.f, 0.f);
}

// ---------------------------------------------------------------------------
// 128x128 MFMA GEMM, BK=64 (8 global_load_lds + 2 barriers per 64-deep
// K-chunk; mod-8 XOR swizzle keeps ds_read_b128 at 2 lanes/bank = free).
// A[m][LDA] bf16, B[n][LDB] bf16 row-major. Direct-store epilogues.
// MODE 1: C bf16 = acc + bias[512z+col], rows scattered (b*8+z)*256+(row&255)
// MODE 2: C bf16 = exp(acc*SCALE), fused row-sum atomicAdd into Ls  (QK -> E)
// MODE 3: C bf16 = (acc + eself*mv)/(eself+L), concat scatter (PV+normalize)
// MODE 5: fp32 partial at Cv[z*cZ + row*N + col]   (Wo split-K slice z)
// ---------------------------------------------------------------------------
template<int MODE, int K, int N, int LDA, int LDB>
__global__ __launch_bounds__(256) void gemm128(
    const short* __restrict__ Abase, const short* __restrict__ Bbase,
    const float* __restrict__ bias, void* __restrict__ Cv,
    const size_t aZ, const int bzsh, const size_t bZ, const size_t cZ,
    float* __restrict__ Ls,
    const float* __restrict__ eselfp, const short* __restrict__ mvbp)
{
  __shared__ short As[8192];  // 128 rows x 64 k
  __shared__ short Bs[8192];
  const int t = threadIdx.x;
  const int w = t >> 6, lane = t & 63, qd = lane >> 4, ln = lane & 15;
  const int z = blockIdx.z;
  const int n0 = blockIdx.x * 128, m0 = blockIdx.y * 128;
  const int wm = (w & 1) * 64, wn = (w >> 1) * 64;

  const short* A  = Abase + (size_t)z * aZ;
  const short* Bp = Bbase + (size_t)(z >> bzsh) * bZ;

  // staging: call c covers phys 16B-slots [c*256, c*256+256): row=slot>>3,
  // phys group = slot&7 holds global group (slot&7)^((row>>1)&7).
  const int rr = t >> 3, gph = t & 7;
  const int gl = gph ^ ((rr >> 1) & 7);   // (c*32)>>1 is 0 mod 8 -> c-invariant
  const short* gaT = A + (size_t)(m0 + rr) * LDA + gl * 8;
  const short* gbT = Bp + (size_t)(n0 + rr) * LDB + gl * 8;

  int aoff[4], boff[4];
#pragma unroll
  for (int mt = 0; mt < 4; ++mt) {
    int r = wm + mt * 16 + ln;
    aoff[mt] = r * 64 + (qd ^ ((r >> 1) & 7)) * 8;
  }
#pragma unroll
  for (int nt = 0; nt < 4; ++nt) {
    int r = wn + nt * 16 + ln;
    boff[nt] = r * 64 + (qd ^ ((r >> 1) & 7)) * 8;
  }

  f32x4 acc[4][4];
#pragma unroll
  for (int mt = 0; mt < 4; ++mt)
#pragma unroll
    for (int nt = 0; nt < 4; ++nt) acc[mt][nt] = (f32x4){0.f, 0.f, 0.f, 0.f};

  for (int kc = 0; kc < K; kc += 64) {
    __syncthreads();
#pragma unroll
    for (int c = 0; c < 4; ++c) {
      gll16(gaT + (size_t)c * 32 * LDA + kc, &As[c * 2048 + w * 512]);
      gll16(gbT + (size_t)c * 32 * LDB + kc, &Bs[c * 2048 + w * 512]);
    }
    __syncthreads();
#pragma unroll
    for (int ch = 0; ch < 2; ++ch) {
      const int x = ch * 32;
      bf16x8 af[4], bfr[4];
#pragma unroll
      for (int mt = 0; mt < 4; ++mt) af[mt] = *(const bf16x8*)&As[aoff[mt] ^ x];
#pragma unroll
      for (int nt = 0; nt < 4; ++nt) bfr[nt] = *(const bf16x8*)&Bs[boff[nt] ^ x];
#pragma unroll
      for (int mt = 0; mt < 4; ++mt)
#pragma unroll
        for (int nt = 0; nt < 4; ++nt)
          acc[mt][nt] = __builtin_amdgcn_mfma_f32_16x16x32_bf16(af[mt], bfr[nt], acc[mt][nt], 0, 0, 0);
    }
  }

  // ---- direct-store epilogues ----
  if constexpr (MODE == 5) {
#pragma unroll
    for (int nt = 0; nt < 4; ++nt) {
      const int col = n0 + wn + nt * 16 + ln;
#pragma unroll
      for (int mt = 0; mt < 4; ++mt)
#pragma unroll
        for (int r = 0; r < 4; ++r) {
          const int row = m0 + wm + mt * 16 + qd * 4 + r;
          ((float*)Cv)[(size_t)z * cZ + (size_t)row * N + col] = acc[mt][nt][r];
        }
    }
  } else if constexpr (MODE == 2) {
#pragma unroll
    for (int mt = 0; mt < 4; ++mt)
#pragma unroll
      for (int nt = 0; nt < 4; ++nt)
#pragma unroll
        for (int r = 0; r < 4; ++r)
          acc[mt][nt][r] = __expf(acc[mt][nt][r] * SCALE);
#pragma unroll
    for (int mt = 0; mt < 4; ++mt)
#pragma unroll
      for (int r = 0; r < 4; ++r) {
        float rsum = acc[mt][0][r] + acc[mt][1][r] + acc[mt][2][r] + acc[mt][3][r];
        rsum += __shfl_xor(rsum, 1);
        rsum += __shfl_xor(rsum, 2);
        rsum += __shfl_xor(rsum, 4);
        rsum += __shfl_xor(rsum, 8);
        if (ln == 0) {
          const int row = m0 + wm + mt * 16 + qd * 4 + r;
          atomicAdd(&Ls[(size_t)z * M_ + row], rsum);
        }
      }
#pragma unroll
    for (int nt = 0; nt < 4; ++nt) {
      const int col = n0 + wn + nt * 16 + ln;
#pragma unroll
      for (int mt = 0; mt < 4; ++mt)
#pragma unroll
        for (int r = 0; r < 4; ++r) {
          const int row = m0 + wm + mt * 16 + qd * 4 + r;
          ((short*)Cv)[(size_t)z * cZ + (size_t)row * N + col] = f2bf(acc[mt][nt][r]);
        }
    }
  } else if constexpr (MODE == 3) {
    const int zb = z >> 3, hh = z & 7;
#pragma unroll
    for (int mt = 0; mt < 4; ++mt)
#pragma unroll
      for (int r = 0; r < 4; ++r) {
        const int row = m0 + wm + mt * 16 + qd * 4 + r;
        const float es = eselfp[(size_t)z * M_ + row];
        const float inv = 1.f / (es + Ls[(size_t)z * M_ + row]);
        const short* mvr = mvbp + ((size_t)(zb * M_ + row)) * P_;
        short* outr = (short*)Cv + ((size_t)(zb * M_ + row)) * (H_ * P_) + (size_t)hh * P_;
#pragma unroll
        for (int nt = 0; nt < 4; ++nt) {
          const int col = n0 + wn + nt * 16 + ln;
          outr[col] = f2bf((acc[mt][nt][r] + es * bf2f(mvr[col])) * inv);
        }
      }
  } else {  // MODE 1
#pragma unroll
    for (int nt = 0; nt < 4; ++nt) {
      const int col = n0 + wn + nt * 16 + ln;
      const float bc = bias[512 * z + col];
#pragma unroll
      for (int mt = 0; mt < 4; ++mt)
#pragma unroll
        for (int r = 0; r < 4; ++r) {
          const int row = m0 + wm + mt * 16 + qd * 4 + r;
          const int bidx = row >> 8, ml = row & 255;
          ((short*)Cv)[((size_t)(bidx * H_ + z) * M_ + ml) * N + col] = f2bf(acc[mt][nt][r] + bc);
        }
    }
  }
}

// ---------------------------------------------------------------------------
// merged K/V projection, BK=64: Ck = A@WkT + bk (row-major, direct store).
// TRANSV=false: V row-major direct. TRANSV=true: V written transposed into
// ivT (B,P,S) via an epilogue LDS transpose that REUSES the K-loop As buffer.
// Block 128m x 64n, wave = 64m x 32n for both outputs.
// ---------------------------------------------------------------------------
template<bool TRANSV>
__global__ __launch_bounds__(256) void proj_kv(
    const short* __restrict__ A,
    const short* __restrict__ WkT, const short* __restrict__ WvT,
    const float* __restrict__ bk, const float* __restrict__ bv,
    short* __restrict__ Ck, short* __restrict__ Cvv)
{
  __shared__ short As[8192];   // 128 x 64
  __shared__ short Bks[4096];  // 64 x 64
  __shared__ short Bvs[4096];
  const int t = threadIdx.x;
  const int w = t >> 6, lane = t & 63, qd = lane >> 4, ln = lane & 15;
  const int n0 = blockIdx.x * 64, m0 = blockIdx.y * 128;
  const int wm = (w & 1) * 64, wn2 = (w >> 1) * 32;

  const int rr = t >> 3, gph = t & 7;
  const int gl = gph ^ ((rr >> 1) & 7);
  const short* gaT = A + (size_t)(m0 + rr) * 512 + gl * 8;
  const short* gbkT = WkT + (size_t)(n0 + rr) * 512 + gl * 8;
  const short* gbvT = WvT + (size_t)(n0 + rr) * 512 + gl * 8;

  int aoff[4], boff[2];
#pragma unroll
  for (int mt = 0; mt < 4; ++mt) {
    int r = wm + mt * 16 + ln;
    aoff[mt] = r * 64 + (qd ^ ((r >> 1) & 7)) * 8;
  }
#pragma unroll
  for (int nt = 0; nt < 2; ++nt) {
    int r = wn2 + nt * 16 + ln;
    boff[nt] = r * 64 + (qd ^ ((r >> 1) & 7)) * 8;
  }

  f32x4 accK[4][2], accV[4][2];
#pragma unroll
  for (int mt = 0; mt < 4; ++mt)
#pragma unroll
    for (int nt = 0; nt < 2; ++nt) {
      accK[mt][nt] = (f32x4){0.f, 0.f, 0.f, 0.f};
      accV[mt][nt] = (f32x4){0.f, 0.f, 0.f, 0.f};
    }

  for (int kc = 0; kc < 512; kc += 64) {
    __syncthreads();
#pragma unroll
    for (int c = 0; c < 4; ++c)
      gll16(gaT + (size_t)c * 32 * 512 + kc, &As[c * 2048 + w * 512]);
#pragma unroll
    for (int c = 0; c < 2; ++c) {
      gll16(gbkT + (size_t)c * 32 * 512 + kc, &Bks[c * 2048 + w * 512]);
      gll16(gbvT + (size_t)c * 32 * 512 + kc, &Bvs[c * 2048 + w * 512]);
    }
    __syncthreads();
#pragma unroll
    for (int ch = 0; ch < 2; ++ch) {
      const int x = ch * 32;
      bf16x8 af[4], bkf[2], bvf[2];
#pragma unroll
      for (int mt = 0; mt < 4; ++mt) af[mt] = *(const bf16x8*)&As[aoff[mt] ^ x];
#pragma unroll
      for (int nt = 0; nt < 2; ++nt) {
        bkf[nt] = *(const bf16x8*)&Bks[boff[nt] ^ x];
        bvf[nt] = *(const bf16x8*)&Bvs[boff[nt] ^ x];
      }
#pragma unroll
      for (int mt = 0; mt < 4; ++mt)
#pragma unroll
        for (int nt = 0; nt < 2; ++nt) {
          accK[mt][nt] = __builtin_amdgcn_mfma_f32_16x16x32_bf16(af[mt], bkf[nt], accK[mt][nt], 0, 0, 0);
          accV[mt][nt] = __builtin_amdgcn_mfma_f32_16x16x32_bf16(af[mt], bvf[nt], accV[mt][nt], 0, 0, 0);
        }
    }
  }

  // ---- K epilogue: direct scattered stores (proven fine in R5)
#pragma unroll
  for (int nt = 0; nt < 2; ++nt) {
    const int col = n0 + wn2 + nt * 16 + ln;
    const float bc = bk[col];
#pragma unroll
    for (int mt = 0; mt < 4; ++mt)
#pragma unroll
      for (int r = 0; r < 4; ++r) {
        const int row = m0 + wm + mt * 16 + qd * 4 + r;
        Ck[(size_t)row * 512 + col] = f2bf(accK[mt][nt][r] + bc);
      }
  }

  // ---- V epilogue
  if constexpr (!TRANSV) {
#pragma unroll
    for (int nt = 0; nt < 2; ++nt) {
      const int col = n0 + wn2 + nt * 16 + ln;
      const float bc = bv[col];
#pragma unroll
      for (int mt = 0; mt < 4; ++mt)
#pragma unroll
        for (int r = 0; r < 4; ++r) {
          const int row = m0 + wm + mt * 16 + qd * 4 + r;
          Cvv[(size_t)row * 512 + col] = f2bf(accV[mt][nt][r] + bc);
        }
    }
  } else {
    // transpose via LDS, reusing As (dead after K-loop). per-wave 32x40 tile.
    __syncthreads();   // all waves done reading As fragments
    short* ep = &As[w * 1280];
    const int lr = lane >> 1, lc16 = (lane & 1) * 16;
#pragma unroll
    for (int pass = 0; pass < 2; ++pass) {
#pragma unroll
      for (int mh = 0; mh < 2; ++mh) {
        const int mt = pass * 2 + mh;
#pragma unroll
        for (int nt = 0; nt < 2; ++nt) {
          const float bc = bv[n0 + wn2 + nt * 16 + ln];
#pragma unroll
          for (int r = 0; r < 4; ++r)
            ep[(nt * 16 + ln) * 40 + mh * 16 + qd * 4 + r] = f2bf(accV[mt][nt][r] + bc);
        }
      }
      LGKM_WAIT();
      const int srow0 = m0 + wm + pass * 32;
      const int bidx = srow0 >> 11;
      const int sloc = (srow0 & 2047) + lc16;
      const int pcol = n0 + wn2 + lr;
      short* outp = Cvv + (size_t)bidx * P_ * S_ + (size_t)pcol * S_ + sloc;
      *(bf16x8*)outp = *(const bf16x8*)&ep[lr * 40 + lc16];
      *(bf16x8*)(outp + 8) = *(const bf16x8*)&ep[lr * 40 + lc16 + 8];
      LGKM_WAIT();
    }
  }
}

// ---------------------------------------------------------------------------
// split-K reduce for Wo: out = sum_z partial[z] + bo[col], fp32
// ---------------------------------------------------------------------------
__global__ __launch_bounds__(256) void reduce_wo(
    const float* __restrict__ partial, const float* __restrict__ bo,
    float* __restrict__ out)
{
  const int idx4 = blockIdx.x * 256 + threadIdx.x;   // float4 index, 262144
  float4 s = ((const float4*)bo)[idx4 & 127];
#pragma unroll
  for (int zz = 0; zz < 4; ++zz) {
    float4 p = ((const float4*)partial)[(size_t)zz * 262144 + idx4];
    s.x += p.x; s.y += p.y; s.z += p.z; s.w += p.w;
  }
  ((float4*)out)[idx4] = s;
}

// ---------------------------------------------------------------------------
// self-score: eself[z*256+m] = exp(scale * q[z][m][:] . mk[b][m][:])
// ---------------------------------------------------------------------------
__global__ __launch_bounds__(256) void selfscore(
    const short* __restrict__ qb, const short* __restrict__ mkb,
    float* __restrict__ eself)
{
  const int z = blockIdx.x, t = threadIdx.x;
  const short* qr = qb + ((size_t)z * M_ + t) * P_;
  const short* mr = mkb + ((size_t)(z >> 3) * M_ + t) * P_;
  float s = 0.f;
#pragma unroll 8
  for (int c = 0; c < P_; c += 8) {
    bf16x8 qv = *(const bf16x8*)(qr + c);
    bf16x8 mv = *(const bf16x8*)(mr + c);
#pragma unroll
    for (int j = 0; j < 8; ++j) s += bf2f(qv[j]) * bf2f(mv[j]);
  }
  eself[(size_t)z * M_ + t] = __expf(s * SCALE);
}

// ---------------------------------------------------------------------------
extern "C" void kernel_launch(void* const* d_in, const int* in_sizes, int n_in,
                              void* d_out, int out_size, void* d_ws, size_t ws_size,
                              hipStream_t stream) {
  const float* input_seq = (const float*)d_in[0];
  const float* memcells  = (const float*)d_in[1];
  const float* Wk = (const float*)d_in[2];
  const float* bk = (const float*)d_in[3];
  const float* Wv = (const float*)d_in[4];
  const float* bv = (const float*)d_in[5];
  const float* Wq = (const float*)d_in[6];
  const float* bq = (const float*)d_in[7];
  const float* Wo = (const float*)d_in[8];
  const float* bo = (const float*)d_in[9];
  float* out = (float*)d_out;

  // ---- workspace carve (shorts). region2 time-shared: {Ab,Mb,W*T} dead
  // before Eb written. 'partial' region reused for Wo split-K fp32 partials.
  short* ws = (short*)d_ws;
  size_t o = 0;
  short* valb = ws + o; o += (size_t)B_ * M_ * H_ * P_;      // 8388608
  short* WoT  = ws + o; o += (size_t)(H_ * P_) * P_;          // 2097152
  short* mvb  = ws + o; o += (size_t)B_ * M_ * P_;            // 1048576
  short* mkb  = ws + o; o += (size_t)B_ * M_ * P_;            // 1048576
  short* qb   = ws + o; o += (size_t)B_ * H_ * M_ * P_;       // 8388608
  short* ivT  = ws + o; o += (size_t)B_ * P_ * S_;            // 8388608
  short* ikb  = ws + o; o += (size_t)B_ * S_ * P_;            // 8388608
  float* partial = (float*)(ws + o); o += (size_t)B_ * H_ * M_ * P_;  // 16 MB
  float* eself = (float*)(ws + o); o += 2 * (size_t)B_ * H_ * M_;
  float* Ls    = (float*)(ws + o); o += 2 * (size_t)B_ * H_ * M_;
  short* region2 = ws + o;                                    // Eb region (64 MB)
  short* Ab  = region2;
  short* Mb  = Ab + (size_t)B_ * S_ * D_;
  short* WkT = Mb + (size_t)B_ * M_ * D_;
  short* WvT = WkT + (size_t)D_ * P_;
  short* WqT = WvT + (size_t)D_ * P_;
  short* Eb  = region2;   // overlaps the above (all dead before E is written)

  dim3 blk(256);

  // casts + weight transposes
  const int n4A = B_ * S_ * D_ / 4;
  const int n4M = B_ * M_ * D_ / 4;
  cast_both<<<dim3((n4A + n4M) / 256), blk, 0, stream>>>(input_seq, Ab, n4A, memcells, Mb);
  wtrans_g<<<dim3(16, 16, 1), blk, 0, stream>>>(Wk, WkT, 512, 512);
  wtrans_g<<<dim3(16, 16, 1), blk, 0, stream>>>(Wv, WvT, 512, 512);
  wtrans_g<<<dim3(16, 16, 8), blk, 0, stream>>>(Wq, WqT, 512, 512);
  wtrans_g<<<dim3(16, 128, 1), blk, 0, stream>>>(Wo, WoT, 4096, 512);

  // merged K/V projections; big one emits ivT directly (transposed V)
  proj_kv<true><<<dim3(8, 128), blk, 0, stream>>>(Ab, WkT, WvT, bk, bv, ikb, ivT);
  proj_kv<false><<<dim3(8, 16), blk, 0, stream>>>(Mb, WkT, WvT, bk, bv, mkb, mvb);

  // q projection: MODE 1, z = h
  gemm128<1, 512, 512, 512, 512><<<dim3(4, 16, 8), blk, 0, stream>>>(
      Mb, WqT, bq, qb, 0, 0, (size_t)D_ * P_, 0, nullptr, nullptr, nullptr);

  // zero Ls, then E = exp(scale * q @ ik^T) with fused row-sum
  zero_f<<<dim3(16), blk, 0, stream>>>(Ls);
  gemm128<2, 512, 2048, 512, 512><<<dim3(16, 2, 64), blk, 0, stream>>>(
      qb, ikb, nullptr, Eb, (size_t)M_ * P_, 3, (size_t)S_ * P_,
      (size_t)M_ * S_, Ls, nullptr, nullptr);

  // eself
  selfscore<<<dim3(64), blk, 0, stream>>>(qb, mkb, eself);

  // val = normalize(E @ iv + eself*mv) fused, concat layout
  gemm128<3, 2048, 512, 2048, 2048><<<dim3(4, 2, 64), blk, 0, stream>>>(
      Eb, ivT, nullptr, valb, (size_t)M_ * S_, 3, (size_t)P_ * S_,
      0, Ls, eself, mvb);

  // Wo: split-K=4 partials (grid 256 blocks), then reduce+bias
  gemm128<5, 1024, 512, 4096, 4096><<<dim3(4, 16, 4), blk, 0, stream>>>(
      valb, WoT, nullptr, partial, 1024, 0, 1024,
      (size_t)2048 * 512, nullptr, nullptr, nullptr);
  reduce_wo<<<dim3(1024), blk, 0, stream>>>(partial, bo, out);
}